// Round 1
// baseline (363.064 us; speedup 1.0000x reference)
//
#include <hip/hip_runtime.h>
#include <hip/hip_bf16.h>

#define TOK   16384       // B*N = 4*4096
#define KD    1024        // DIM
#define NQKV  3072
#define SEQL  4096
#define ATT_SCALE 0.125f  // 64^-0.5

typedef __attribute__((ext_vector_type(4))) float f32x4;
typedef __attribute__((ext_vector_type(8))) short bf16x8;

__device__ __forceinline__ unsigned short f2b(float f){
    union { float f; unsigned u; } x; x.f = f;
    return (unsigned short)((x.u + 0x7FFFu + ((x.u >> 16) & 1u)) >> 16);
}
__device__ __forceinline__ float b2f(unsigned short s){
    union { unsigned u; float f; } x; x.u = ((unsigned)s) << 16;
    return x.f;
}
__device__ __forceinline__ bf16x8 lds8(const unsigned short* p){
    union { uint2 u[2]; bf16x8 v; } t;
    t.u[0] = *(const uint2*)p;
    t.u[1] = *(const uint2*)(p + 4);
    return t.v;
}

// C[M x Nn] = A[M x 1024] * Bw[Nn x 1024]^T + bias.  Tiles 128x128, BK=32.
// 256 threads = 4 waves in 2x2, each wave does 64x64 via 4x4 frags of 16x16x32.
template<bool A_BF16, bool OUT_BF16>
__global__ __launch_bounds__(256) void gemm_kernel(const void* __restrict__ Ap,
        const float* __restrict__ Bw, const float* __restrict__ bias,
        void* __restrict__ Cp, int Nn)
{
    // pad rows to 40 elems (80B): 2-way bank aliasing only (free), 8B-aligned frag reads
    __shared__ unsigned short As[128 * 40];
    __shared__ unsigned short Bs[128 * 40];
    const int tid = threadIdx.x, lane = tid & 63;
    const int wv = tid >> 6, wm = wv >> 1, wn = wv & 1;
    const int mBase = blockIdx.y * 128, cBase = blockIdx.x * 128;
    const int srow = tid >> 1, scol = (tid & 1) * 16;

    f32x4 acc[4][4];
    #pragma unroll
    for (int m = 0; m < 4; m++)
        #pragma unroll
        for (int n = 0; n < 4; n++) acc[m][n] = (f32x4)0.f;

    for (int kt = 0; kt < KD; kt += 32) {
        // ---- stage A tile (128x32) ----
        if (A_BF16) {
            const unsigned short* Arow = (const unsigned short*)Ap + (size_t)(mBase + srow) * KD + kt + scol;
            uint4 v0 = *(const uint4*)Arow;
            uint4 v1 = *(const uint4*)(Arow + 8);
            unsigned short* d = &As[srow * 40 + scol];
            *(uint2*)(d)      = make_uint2(v0.x, v0.y);
            *(uint2*)(d + 4)  = make_uint2(v0.z, v0.w);
            *(uint2*)(d + 8)  = make_uint2(v1.x, v1.y);
            *(uint2*)(d + 12) = make_uint2(v1.z, v1.w);
        } else {
            const float* Arow = (const float*)Ap + (size_t)(mBase + srow) * KD + kt + scol;
            unsigned short tmp[16];
            #pragma unroll
            for (int i = 0; i < 4; i++) {
                float4 f = *(const float4*)(Arow + 4 * i);
                tmp[4*i]   = f2b(f.x); tmp[4*i+1] = f2b(f.y);
                tmp[4*i+2] = f2b(f.z); tmp[4*i+3] = f2b(f.w);
            }
            unsigned short* d = &As[srow * 40 + scol];
            #pragma unroll
            for (int i = 0; i < 4; i++) *(ushort4*)(d + 4 * i) = *(ushort4*)&tmp[4 * i];
        }
        // ---- stage B tile (128x32), always fp32 weights ----
        {
            const float* Brow = Bw + (size_t)(cBase + srow) * KD + kt + scol;
            unsigned short tmp[16];
            #pragma unroll
            for (int i = 0; i < 4; i++) {
                float4 f = *(const float4*)(Brow + 4 * i);
                tmp[4*i]   = f2b(f.x); tmp[4*i+1] = f2b(f.y);
                tmp[4*i+2] = f2b(f.z); tmp[4*i+3] = f2b(f.w);
            }
            unsigned short* d = &Bs[srow * 40 + scol];
            #pragma unroll
            for (int i = 0; i < 4; i++) *(ushort4*)(d + 4 * i) = *(ushort4*)&tmp[4 * i];
        }
        __syncthreads();

        const int koff = (lane >> 4) * 8, rl = lane & 15;
        bf16x8 af[4], bg[4];
        #pragma unroll
        for (int m = 0; m < 4; m++) af[m] = lds8(&As[(wm * 64 + m * 16 + rl) * 40 + koff]);
        #pragma unroll
        for (int n = 0; n < 4; n++) bg[n] = lds8(&Bs[(wn * 64 + n * 16 + rl) * 40 + koff]);
        #pragma unroll
        for (int m = 0; m < 4; m++)
            #pragma unroll
            for (int n = 0; n < 4; n++)
                acc[m][n] = __builtin_amdgcn_mfma_f32_16x16x32_bf16(af[m], bg[n], acc[m][n], 0, 0, 0);
        __syncthreads();
    }

    // epilogue: C/D layout col=lane&15, row=(lane>>4)*4+reg
    #pragma unroll
    for (int n = 0; n < 4; n++) {
        const int col = cBase + wn * 64 + n * 16 + (lane & 15);
        const float bv = bias[col];
        #pragma unroll
        for (int m = 0; m < 4; m++) {
            const int row0 = mBase + wm * 64 + m * 16 + (lane >> 4) * 4;
            #pragma unroll
            for (int i = 0; i < 4; i++) {
                const float val = acc[m][n][i] + bv;
                if (OUT_BF16) ((unsigned short*)Cp)[(size_t)(row0 + i) * Nn + col] = f2b(val);
                else          ((float*)Cp)[(size_t)(row0 + i) * Nn + col] = val;
            }
        }
    }
}

// Per-token head-attention. One wave per token, 4 tokens/block.
// qkv row layout: q[h][d]=e(h*64+d), k=1024+..., v=2048+...  LDS rows padded 64->72.
__global__ __launch_bounds__(256) void attn_kernel(const unsigned short* __restrict__ qkv,
                                                   unsigned short* __restrict__ outp)
{
    __shared__ __align__(16) unsigned short qs[4][48 * 72];
    __shared__ float ps[4][16 * 17];
    const int tid = threadIdx.x, w = tid >> 6, lane = tid & 63;
    const int t = blockIdx.x * 4 + w;

    const unsigned short* src = qkv + (size_t)t * NQKV;
    #pragma unroll
    for (int i = 0; i < 6; i++) {
        const int e = i * 512 + lane * 8;
        uint4 v = *(const uint4*)(src + e);
        *(uint4*)&qs[w][(e >> 6) * 72 + (e & 63)] = v;
    }
    __syncthreads();

    // S[h][g] = scale * dot(q_h, k_g); lane (h=lane&15, g0=lane>>4) owns g=4*g0..4*g0+3
    const int h = lane & 15, g0 = lane >> 4;
    uint4 qv[8];
    #pragma unroll
    for (int i = 0; i < 8; i++) qv[i] = *(const uint4*)&qs[w][h * 72 + i * 8];
    float s[4];
    #pragma unroll
    for (int i = 0; i < 4; i++) {
        const int g = g0 * 4 + i;
        float a = 0.f;
        #pragma unroll
        for (int c = 0; c < 8; c++) {
            uint4 kv = *(const uint4*)&qs[w][(16 + g) * 72 + c * 8];
            uint qa[4] = {qv[c].x, qv[c].y, qv[c].z, qv[c].w};
            uint ka[4] = {kv.x, kv.y, kv.z, kv.w};
            #pragma unroll
            for (int u = 0; u < 4; u++) {
                a += b2f((unsigned short)qa[u]) * b2f((unsigned short)ka[u]);
                a += b2f((unsigned short)(qa[u] >> 16)) * b2f((unsigned short)(ka[u] >> 16));
            }
        }
        s[i] = a * ATT_SCALE;
    }
    // softmax over g (16), distributed over 4 lanes (xor 16/32 groups share h)
    float mx = fmaxf(fmaxf(s[0], s[1]), fmaxf(s[2], s[3]));
    mx = fmaxf(mx, __shfl_xor(mx, 16, 64));
    mx = fmaxf(mx, __shfl_xor(mx, 32, 64));
    float p[4], sm = 0.f;
    #pragma unroll
    for (int i = 0; i < 4; i++) { p[i] = __expf(s[i] - mx); sm += p[i]; }
    sm += __shfl_xor(sm, 16, 64);
    sm += __shfl_xor(sm, 32, 64);
    const float inv = 1.f / sm;
    #pragma unroll
    for (int i = 0; i < 4; i++) ps[w][h * 17 + g0 * 4 + i] = p[i] * inv;
    __syncthreads();

    // out[h2][d] = sum_g P[h2][g] * v[g][d]; lane owns (h2=lane>>2, d = (lane&3)*16 + 0..15)
    const int h2 = lane >> 2, db = (lane & 3) * 16;
    float pr[16];
    #pragma unroll
    for (int g = 0; g < 16; g++) pr[g] = ps[w][h2 * 17 + g];
    float acc[16];
    #pragma unroll
    for (int j = 0; j < 16; j++) acc[j] = 0.f;
    #pragma unroll
    for (int g = 0; g < 16; g++) {
        const unsigned short* vp = &qs[w][(32 + g) * 72 + db];
        uint4 v0 = *(const uint4*)vp;
        uint4 v1 = *(const uint4*)(vp + 8);
        const float pg = pr[g];
        uint va[8] = {v0.x, v0.y, v0.z, v0.w, v1.x, v1.y, v1.z, v1.w};
        #pragma unroll
        for (int u = 0; u < 8; u++) {
            acc[2*u]   += pg * b2f((unsigned short)va[u]);
            acc[2*u+1] += pg * b2f((unsigned short)(va[u] >> 16));
        }
    }
    // scrambled store: (b,h,n,d) -> row h2*256 + (n>>4), col (n&15)*64 + d
    const int b = t >> 12, n = t & 4095;
    const int n1 = h2 * 256 + (n >> 4);
    const int c0 = (n & 15) * 64 + db;
    union { unsigned short u[16]; uint4 v[2]; } st;
    #pragma unroll
    for (int j = 0; j < 16; j++) st.u[j] = f2b(acc[j]);
    unsigned short* dst = outp + ((size_t)(b * SEQL + n1)) * 1024 + c0;
    *(uint4*)dst       = st.v[0];
    *(uint4*)(dst + 8) = st.v[1];
}

extern "C" void kernel_launch(void* const* d_in, const int* in_sizes, int n_in,
                              void* d_out, int out_size, void* d_ws, size_t ws_size,
                              hipStream_t stream)
{
    const float* x      = (const float*)d_in[0];
    const float* qkv_w  = (const float*)d_in[1];
    const float* qkv_b  = (const float*)d_in[2];
    const float* proj_w = (const float*)d_in[3];
    const float* proj_b = (const float*)d_in[4];

    unsigned short* qkv = (unsigned short*)d_ws;            // 16384*3072 bf16 = 100.7 MB
    unsigned short* att = qkv + (size_t)TOK * NQKV;         // 16384*1024 bf16 = 33.5 MB

    gemm_kernel<false, true><<<dim3(NQKV / 128, TOK / 128), dim3(256), 0, stream>>>(
        x, qkv_w, qkv_b, qkv, NQKV);
    attn_kernel<<<dim3(TOK / 4), dim3(256), 0, stream>>>(qkv, att);
    gemm_kernel<true, false><<<dim3(KD / 128, TOK / 128), dim3(256), 0, stream>>>(
        att, proj_w, proj_b, (float*)d_out, KD);
}

// Round 2
// 236.920 us; speedup vs baseline: 1.5324x; 1.5324x over previous
//
#include <hip/hip_runtime.h>
#include <hip/hip_bf16.h>

#define TOK   16384       // B*N = 4*4096
#define KD    1024        // DIM
#define NQKV  3072
#define SEQL  4096
#define ATT_SCALE 0.125f  // 64^-0.5

typedef __attribute__((ext_vector_type(4))) float f32x4;
typedef __attribute__((ext_vector_type(8))) short bf16x8;

__device__ __forceinline__ unsigned short f2b(float f){
    union { float f; unsigned u; } x; x.f = f;
    return (unsigned short)((x.u + 0x7FFFu + ((x.u >> 16) & 1u)) >> 16);
}
__device__ __forceinline__ float b2f(unsigned short s){
    union { unsigned u; float f; } x; x.u = ((unsigned)s) << 16;
    return x.f;
}
__device__ __forceinline__ bf16x8 lds8(const unsigned short* p){
    union { uint4 u; bf16x8 v; } t; t.u = *(const uint4*)p; return t.v;
}
__device__ __forceinline__ void glds16(const void* g, void* l){
    __builtin_amdgcn_global_load_lds((const __attribute__((address_space(1))) unsigned*)g,
                                     (__attribute__((address_space(3))) unsigned*)l, 16, 0, 0);
}

// fp32 -> bf16 convert, 8 elems/thread
__global__ __launch_bounds__(256) void cvt_kernel(const float* __restrict__ in,
                                                  unsigned short* __restrict__ out, int n)
{
    int i = (blockIdx.x * 256 + threadIdx.x) * 8;
    if (i >= n) return;
    float4 a = *(const float4*)(in + i);
    float4 b = *(const float4*)(in + i + 4);
    union { unsigned short u[8]; uint4 v; } t;
    t.u[0]=f2b(a.x); t.u[1]=f2b(a.y); t.u[2]=f2b(a.z); t.u[3]=f2b(a.w);
    t.u[4]=f2b(b.x); t.u[5]=f2b(b.y); t.u[6]=f2b(b.z); t.u[7]=f2b(b.w);
    *(uint4*)(out + i) = t.v;
}

// C[M x Nn] = A[M x 1024]_bf16 * Bw[Nn x 1024]_bf16^T + bias. m97 structure:
// 128x128 tile, BK=32, 4 waves (2x2), global_load_lds w=16, dbuf LDS,
// k-slot swizzle slot' = slot ^ ((row>>1)&3) (inverse-swz source + swz read).
template<bool OUT_BF16>
__global__ __launch_bounds__(256) void gemm_kernel(const unsigned short* __restrict__ A,
        const unsigned short* __restrict__ Bw, const float* __restrict__ bias,
        void* __restrict__ Cp, int Nn)
{
    __shared__ unsigned short As[2][128 * 32];
    __shared__ unsigned short Bs[2][128 * 32];
    const int tid = threadIdx.x, lane = tid & 63;
    const int w = tid >> 6, wm = w >> 1, wn = w & 1;
    const int mBase = blockIdx.y * 128, cBase = blockIdx.x * 128;

    // staging: inst j covers rows j*64 + w*16 + lane/4, source k-slot inverse-swizzled
    const int srow = w * 16 + (lane >> 2);
    const int sslot = (lane & 3) ^ ((lane >> 3) & 3);   // slot ^ ((row>>1)&3), row=lane>>2
    const unsigned short* Asrc = A  + (size_t)(mBase + srow) * KD + sslot * 8;
    const unsigned short* Bsrc = Bw + (size_t)(cBase + srow) * KD + sslot * 8;
    const int ldsOff = w * 512;   // shorts; wave-uniform

    f32x4 acc[4][4];
    #pragma unroll
    for (int m = 0; m < 4; m++)
        #pragma unroll
        for (int n = 0; n < 4; n++) acc[m][n] = (f32x4)0.f;

    // fragment read addressing (swizzled k-slot)
    const int rl = lane & 15;
    const int kslot = lane >> 4;                 // logical k-slot 0..3
    const int rsw = (lane >> 1) & 3;             // (row>>1)&3 since row%16==rl

    #pragma unroll
    for (int j = 0; j < 2; j++) {
        glds16(Asrc + (size_t)j * 64 * KD, (void*)&As[0][j * 2048 + ldsOff]);
        glds16(Bsrc + (size_t)j * 64 * KD, (void*)&Bs[0][j * 2048 + ldsOff]);
    }

    int buf = 0;
    for (int kt = 0; kt < KD; kt += 32) {
        __syncthreads();   // drains vmcnt -> staging of buf complete; readers of buf^1 done
        if (kt + 32 < KD) {
            #pragma unroll
            for (int j = 0; j < 2; j++) {
                glds16(Asrc + (size_t)j * 64 * KD + kt + 32, (void*)&As[buf ^ 1][j * 2048 + ldsOff]);
                glds16(Bsrc + (size_t)j * 64 * KD + kt + 32, (void*)&Bs[buf ^ 1][j * 2048 + ldsOff]);
            }
        }
        bf16x8 af[4], bg[4];
        #pragma unroll
        for (int m = 0; m < 4; m++) {
            const int row = wm * 64 + m * 16 + rl;
            af[m] = lds8(&As[buf][row * 32 + ((kslot ^ rsw) * 8)]);
        }
        #pragma unroll
        for (int n = 0; n < 4; n++) {
            const int row = wn * 64 + n * 16 + rl;
            bg[n] = lds8(&Bs[buf][row * 32 + ((kslot ^ rsw) * 8)]);
        }
        #pragma unroll
        for (int m = 0; m < 4; m++)
            #pragma unroll
            for (int n = 0; n < 4; n++)
                acc[m][n] = __builtin_amdgcn_mfma_f32_16x16x32_bf16(af[m], bg[n], acc[m][n], 0, 0, 0);
        buf ^= 1;
    }

    // epilogue: C/D layout col=lane&15, row=(lane>>4)*4+reg
    #pragma unroll
    for (int n = 0; n < 4; n++) {
        const int col = cBase + wn * 64 + n * 16 + (lane & 15);
        const float bv = bias[col];
        #pragma unroll
        for (int m = 0; m < 4; m++) {
            const int row0 = mBase + wm * 64 + m * 16 + (lane >> 4) * 4;
            #pragma unroll
            for (int i = 0; i < 4; i++) {
                const float val = acc[m][n][i] + bv;
                if (OUT_BF16) ((unsigned short*)Cp)[(size_t)(row0 + i) * Nn + col] = f2b(val);
                else          ((float*)Cp)[(size_t)(row0 + i) * Nn + col] = val;
            }
        }
    }
}

// Per-token head-attention. One wave per token, 4 tokens/block.
__global__ __launch_bounds__(256) void attn_kernel(const unsigned short* __restrict__ qkv,
                                                   unsigned short* __restrict__ outp)
{
    __shared__ __align__(16) unsigned short qs[4][48 * 72];
    __shared__ float ps[4][16 * 17];
    const int tid = threadIdx.x, w = tid >> 6, lane = tid & 63;
    const int t = blockIdx.x * 4 + w;

    const unsigned short* src = qkv + (size_t)t * NQKV;
    #pragma unroll
    for (int i = 0; i < 6; i++) {
        const int e = i * 512 + lane * 8;
        uint4 v = *(const uint4*)(src + e);
        *(uint4*)&qs[w][(e >> 6) * 72 + (e & 63)] = v;
    }
    __syncthreads();

    const int h = lane & 15, g0 = lane >> 4;
    uint4 qv[8];
    #pragma unroll
    for (int i = 0; i < 8; i++) qv[i] = *(const uint4*)&qs[w][h * 72 + i * 8];
    float s[4];
    #pragma unroll
    for (int i = 0; i < 4; i++) {
        const int g = g0 * 4 + i;
        float a = 0.f;
        #pragma unroll
        for (int c = 0; c < 8; c++) {
            uint4 kv = *(const uint4*)&qs[w][(16 + g) * 72 + c * 8];
            uint qa[4] = {qv[c].x, qv[c].y, qv[c].z, qv[c].w};
            uint ka[4] = {kv.x, kv.y, kv.z, kv.w};
            #pragma unroll
            for (int u = 0; u < 4; u++) {
                a += b2f((unsigned short)qa[u]) * b2f((unsigned short)ka[u]);
                a += b2f((unsigned short)(qa[u] >> 16)) * b2f((unsigned short)(ka[u] >> 16));
            }
        }
        s[i] = a * ATT_SCALE;
    }
    float mx = fmaxf(fmaxf(s[0], s[1]), fmaxf(s[2], s[3]));
    mx = fmaxf(mx, __shfl_xor(mx, 16, 64));
    mx = fmaxf(mx, __shfl_xor(mx, 32, 64));
    float p[4], sm = 0.f;
    #pragma unroll
    for (int i = 0; i < 4; i++) { p[i] = __expf(s[i] - mx); sm += p[i]; }
    sm += __shfl_xor(sm, 16, 64);
    sm += __shfl_xor(sm, 32, 64);
    const float inv = 1.f / sm;
    #pragma unroll
    for (int i = 0; i < 4; i++) ps[w][h * 17 + g0 * 4 + i] = p[i] * inv;
    __syncthreads();

    const int h2 = lane >> 2, db = (lane & 3) * 16;
    float pr[16];
    #pragma unroll
    for (int g = 0; g < 16; g++) pr[g] = ps[w][h2 * 17 + g];
    float acc[16];
    #pragma unroll
    for (int j = 0; j < 16; j++) acc[j] = 0.f;
    #pragma unroll
    for (int g = 0; g < 16; g++) {
        const unsigned short* vp = &qs[w][(32 + g) * 72 + db];
        uint4 v0 = *(const uint4*)vp;
        uint4 v1 = *(const uint4*)(vp + 8);
        const float pg = pr[g];
        uint va[8] = {v0.x, v0.y, v0.z, v0.w, v1.x, v1.y, v1.z, v1.w};
        #pragma unroll
        for (int u = 0; u < 8; u++) {
            acc[2*u]   += pg * b2f((unsigned short)va[u]);
            acc[2*u+1] += pg * b2f((unsigned short)(va[u] >> 16));
        }
    }
    const int b = t >> 12, n = t & 4095;
    const int n1 = h2 * 256 + (n >> 4);
    const int c0 = (n & 15) * 64 + db;
    union { unsigned short u[16]; uint4 v[2]; } st;
    #pragma unroll
    for (int j = 0; j < 16; j++) st.u[j] = f2b(acc[j]);
    unsigned short* dst = outp + ((size_t)(b * SEQL + n1)) * 1024 + c0;
    *(uint4*)dst       = st.v[0];
    *(uint4*)(dst + 8) = st.v[1];
}

extern "C" void kernel_launch(void* const* d_in, const int* in_sizes, int n_in,
                              void* d_out, int out_size, void* d_ws, size_t ws_size,
                              hipStream_t stream)
{
    const float* x      = (const float*)d_in[0];
    const float* qkv_w  = (const float*)d_in[1];
    const float* qkv_b  = (const float*)d_in[2];
    const float* proj_w = (const float*)d_in[3];
    const float* proj_b = (const float*)d_in[4];

    // ws layout (bf16 elements). region0 is x_bf16 during QKV GEMM, then reused
    // as the attention output (both TOK*KD elems).
    unsigned short* xb  = (unsigned short*)d_ws;            // 33.5 MB
    unsigned short* qkv = xb + (size_t)TOK * KD;            // 100.7 MB
    unsigned short* qwb = qkv + (size_t)TOK * NQKV;         // 6.3 MB
    unsigned short* pwb = qwb + (size_t)NQKV * KD;          // 2.1 MB
    unsigned short* att = xb;                               // alias (after QKV GEMM)

    cvt_kernel<<<dim3(TOK * KD / 2048), dim3(256), 0, stream>>>(x, xb, TOK * KD);
    cvt_kernel<<<dim3(NQKV * KD / 2048), dim3(256), 0, stream>>>(qkv_w, qwb, NQKV * KD);
    cvt_kernel<<<dim3(KD * KD / 2048), dim3(256), 0, stream>>>(proj_w, pwb, KD * KD);

    gemm_kernel<true><<<dim3(NQKV / 128, TOK / 128), dim3(256), 0, stream>>>(
        xb, qwb, qkv_b, qkv, NQKV);
    attn_kernel<<<dim3(TOK / 4), dim3(256), 0, stream>>>(qkv, att);
    gemm_kernel<false><<<dim3(KD / 128, TOK / 128), dim3(256), 0, stream>>>(
        att, pwb, proj_b, (float*)d_out, KD);
}

// Round 3
// 215.624 us; speedup vs baseline: 1.6838x; 1.0988x over previous
//
#include <hip/hip_runtime.h>
#include <hip/hip_bf16.h>

#define TOK   16384       // B*N = 4*4096
#define KD    1024        // DIM
#define NQKV  3072
#define SEQL  4096
#define ATT_SCALE 0.125f  // 64^-0.5

typedef __attribute__((ext_vector_type(4))) float f32x4;
typedef __attribute__((ext_vector_type(8))) short bf16x8;

__device__ __forceinline__ unsigned short f2b(float f){
    union { float f; unsigned u; } x; x.f = f;
    return (unsigned short)((x.u + 0x7FFFu + ((x.u >> 16) & 1u)) >> 16);
}
__device__ __forceinline__ float b2f(unsigned short s){
    union { unsigned u; float f; } x; x.u = ((unsigned)s) << 16;
    return x.f;
}
__device__ __forceinline__ bf16x8 lds8(const unsigned short* p){
    union { uint4 u; bf16x8 v; } t; t.u = *(const uint4*)p; return t.v;
}
__device__ __forceinline__ void glds16(const void* g, void* l){
    __builtin_amdgcn_global_load_lds((const __attribute__((address_space(1))) unsigned*)g,
                                     (__attribute__((address_space(3))) unsigned*)l, 16, 0, 0);
}

// fp32 -> bf16 convert, 8 elems/thread
__global__ __launch_bounds__(256) void cvt_kernel(const float* __restrict__ in,
                                                  unsigned short* __restrict__ out, int n)
{
    int i = (blockIdx.x * 256 + threadIdx.x) * 8;
    if (i >= n) return;
    float4 a = *(const float4*)(in + i);
    float4 b = *(const float4*)(in + i + 4);
    union { unsigned short u[8]; uint4 v; } t;
    t.u[0]=f2b(a.x); t.u[1]=f2b(a.y); t.u[2]=f2b(a.z); t.u[3]=f2b(a.w);
    t.u[4]=f2b(b.x); t.u[5]=f2b(b.y); t.u[6]=f2b(b.z); t.u[7]=f2b(b.w);
    *(uint4*)(out + i) = t.v;
}

// ===== 256x256 8-phase GEMM (m201 template, plain HIP) =====
// C[M x Nn] = A[M x 1024]_bf16 * Bw[Nn x 1024]_bf16^T + bias.
// 512 threads = 8 waves (2M x 4N), per-wave 128x64 out, BK=64, dbuf 128KiB LDS.
// Swizzle: lds slot seg holds global seg (seg ^ (row&7)); reads XOR the same.
template<bool OUT_BF16>
__global__ __launch_bounds__(512, 2) void gemm256(const unsigned short* __restrict__ A,
        const unsigned short* __restrict__ Bw, const float* __restrict__ bias,
        void* __restrict__ Cp, int Nn)
{
    extern __shared__ unsigned short sm[];
    unsigned short* As = sm;            // [2][256][64] shorts
    unsigned short* Bs = sm + 32768;

    const int tid = threadIdx.x, lane = tid & 63;
    const int w = tid >> 6, wm = w >> 2, wn = w & 3;
    const int rl = lane & 15, kslot = lane >> 4;

    // T1: bijective XCD swizzle (nwg % 8 == 0 for both GEMMs)
    const int gx = gridDim.x;
    const int nwg = gx * gridDim.y;
    int id = blockIdx.y * gx + blockIdx.x;
    id = (id & 7) * (nwg >> 3) + (id >> 3);
    const int cBase = (id % gx) * 256;
    const int mBase = (id / gx) * 256;

    // staging: idx = chunk*512 + tid; row = idx>>3 (chunk*64 + tid>>3), seg = tid&7
    // source seg pre-swizzled: seg ^ (row&7), row&7 == (tid>>3)&7 for all chunks
    const int srcseg = ((tid & 7) ^ ((tid >> 3) & 7)) * 8;
    const unsigned short* Ag = A  + (size_t)(mBase + (tid >> 3)) * KD + srcseg;
    const unsigned short* Bg = Bw + (size_t)(cBase + (tid >> 3)) * KD + srcseg;

    // fragment read bases (swizzled seg)
    const int sA = (wm * 128 + rl) * 64;   // + m*1024 + skK
    const int sB = (wn * 64  + rl) * 64;   // + n*1024 + skK
    const int xk = rl & 7;
    const int sk0 = (kslot ^ xk) * 8;          // k-step 0 (cols 0..31)
    const int sk1 = ((4 + kslot) ^ xk) * 8;    // k-step 1 (cols 32..63)

    f32x4 acc[8][4];
    #pragma unroll
    for (int m = 0; m < 8; m++)
        #pragma unroll
        for (int n = 0; n < 4; n++) acc[m][n] = (f32x4)0.f;

#define STAGE_A(bb, kk) { \
        glds16(Ag + (kk),          As + (bb)*16384 + tid*8); \
        glds16(Ag + 64*KD + (kk),  As + (bb)*16384 + 4096  + tid*8); \
        glds16(Ag + 128*KD + (kk), As + (bb)*16384 + 8192  + tid*8); \
        glds16(Ag + 192*KD + (kk), As + (bb)*16384 + 12288 + tid*8); }
#define STAGE_B(bb, kk) { \
        glds16(Bg + (kk),          Bs + (bb)*16384 + tid*8); \
        glds16(Bg + 64*KD + (kk),  Bs + (bb)*16384 + 4096  + tid*8); \
        glds16(Bg + 128*KD + (kk), Bs + (bb)*16384 + 8192  + tid*8); \
        glds16(Bg + 192*KD + (kk), Bs + (bb)*16384 + 12288 + tid*8); }

    STAGE_A(0, 0)
    STAGE_B(0, 0)
    asm volatile("s_waitcnt vmcnt(0)" ::: "memory");
    __builtin_amdgcn_s_barrier();

    bf16x8 af[4][2], bfr[4][2];
    int buf = 0;
    for (int kt = 0; kt < KD; kt += 64) {
        const unsigned short* a = As + buf * 16384;
        const unsigned short* b = Bs + buf * 16384;
        const int nkt = kt + 64;
        // ---------- P0: Q(0,0) ----------
        #pragma unroll
        for (int m = 0; m < 4; m++) {
            af[m][0] = lds8(a + sA + m * 1024 + sk0);
            af[m][1] = lds8(a + sA + m * 1024 + sk1);
        }
        #pragma unroll
        for (int n = 0; n < 2; n++) {
            bfr[n][0] = lds8(b + sB + n * 1024 + sk0);
            bfr[n][1] = lds8(b + sB + n * 1024 + sk1);
        }
        if (nkt < KD) STAGE_A(buf ^ 1, nkt)
        __builtin_amdgcn_s_barrier();
        asm volatile("s_waitcnt lgkmcnt(0)" ::: "memory");
        __builtin_amdgcn_sched_barrier(0);
        __builtin_amdgcn_s_setprio(1);
        #pragma unroll
        for (int m = 0; m < 4; m++)
            #pragma unroll
            for (int n = 0; n < 2; n++) {
                acc[m][n] = __builtin_amdgcn_mfma_f32_16x16x32_bf16(af[m][0], bfr[n][0], acc[m][n], 0, 0, 0);
                acc[m][n] = __builtin_amdgcn_mfma_f32_16x16x32_bf16(af[m][1], bfr[n][1], acc[m][n], 0, 0, 0);
            }
        __builtin_amdgcn_s_setprio(0);
        __builtin_amdgcn_s_barrier();
        // ---------- P1: Q(0,1) ----------
        #pragma unroll
        for (int n = 2; n < 4; n++) {
            bfr[n][0] = lds8(b + sB + n * 1024 + sk0);
            bfr[n][1] = lds8(b + sB + n * 1024 + sk1);
        }
        if (nkt < KD) STAGE_B(buf ^ 1, nkt)
        __builtin_amdgcn_s_barrier();
        asm volatile("s_waitcnt lgkmcnt(0)" ::: "memory");
        __builtin_amdgcn_sched_barrier(0);
        __builtin_amdgcn_s_setprio(1);
        #pragma unroll
        for (int m = 0; m < 4; m++)
            #pragma unroll
            for (int n = 2; n < 4; n++) {
                acc[m][n] = __builtin_amdgcn_mfma_f32_16x16x32_bf16(af[m][0], bfr[n][0], acc[m][n], 0, 0, 0);
                acc[m][n] = __builtin_amdgcn_mfma_f32_16x16x32_bf16(af[m][1], bfr[n][1], acc[m][n], 0, 0, 0);
            }
        __builtin_amdgcn_s_setprio(0);
        __builtin_amdgcn_s_barrier();
        // ---------- P2: Q(1,0) ----------
        #pragma unroll
        for (int m = 0; m < 4; m++) {
            af[m][0] = lds8(a + sA + (m + 4) * 1024 + sk0);
            af[m][1] = lds8(a + sA + (m + 4) * 1024 + sk1);
        }
        __builtin_amdgcn_s_barrier();
        asm volatile("s_waitcnt lgkmcnt(0)" ::: "memory");
        __builtin_amdgcn_sched_barrier(0);
        __builtin_amdgcn_s_setprio(1);
        #pragma unroll
        for (int m = 0; m < 4; m++)
            #pragma unroll
            for (int n = 0; n < 2; n++) {
                acc[4 + m][n] = __builtin_amdgcn_mfma_f32_16x16x32_bf16(af[m][0], bfr[n][0], acc[4 + m][n], 0, 0, 0);
                acc[4 + m][n] = __builtin_amdgcn_mfma_f32_16x16x32_bf16(af[m][1], bfr[n][1], acc[4 + m][n], 0, 0, 0);
            }
        __builtin_amdgcn_s_setprio(0);
        __builtin_amdgcn_s_barrier();
        // ---------- P3: Q(1,1) ----------
        __builtin_amdgcn_s_setprio(1);
        #pragma unroll
        for (int m = 0; m < 4; m++)
            #pragma unroll
            for (int n = 2; n < 4; n++) {
                acc[4 + m][n] = __builtin_amdgcn_mfma_f32_16x16x32_bf16(af[m][0], bfr[n][0], acc[4 + m][n], 0, 0, 0);
                acc[4 + m][n] = __builtin_amdgcn_mfma_f32_16x16x32_bf16(af[m][1], bfr[n][1], acc[4 + m][n], 0, 0, 0);
            }
        __builtin_amdgcn_s_setprio(0);
        asm volatile("s_waitcnt vmcnt(0)" ::: "memory");   // next tile staged
        __builtin_amdgcn_s_barrier();
        buf ^= 1;
    }
#undef STAGE_A
#undef STAGE_B

    // epilogue: C/D layout col=lane&15, row=(lane>>4)*4+reg
    #pragma unroll
    for (int n = 0; n < 4; n++) {
        const int col = cBase + wn * 64 + n * 16 + rl;
        const float bv = bias[col];
        #pragma unroll
        for (int m = 0; m < 8; m++) {
            const int row0 = mBase + wm * 128 + m * 16 + kslot * 4;
            #pragma unroll
            for (int i = 0; i < 4; i++) {
                const float val = acc[m][n][i] + bv;
                if (OUT_BF16) ((unsigned short*)Cp)[(size_t)(row0 + i) * Nn + col] = f2b(val);
                else          ((float*)Cp)[(size_t)(row0 + i) * Nn + col] = val;
            }
        }
    }
}

// Per-token head-attention. One wave per token, 4 tokens/block.
__global__ __launch_bounds__(256) void attn_kernel(const unsigned short* __restrict__ qkv,
                                                   unsigned short* __restrict__ outp)
{
    __shared__ __align__(16) unsigned short qs[4][48 * 72];
    __shared__ float ps[4][16 * 17];
    const int tid = threadIdx.x, w = tid >> 6, lane = tid & 63;
    const int t = blockIdx.x * 4 + w;

    const unsigned short* src = qkv + (size_t)t * NQKV;
    #pragma unroll
    for (int i = 0; i < 6; i++) {
        const int e = i * 512 + lane * 8;
        uint4 v = *(const uint4*)(src + e);
        *(uint4*)&qs[w][(e >> 6) * 72 + (e & 63)] = v;
    }
    __syncthreads();

    const int h = lane & 15, g0 = lane >> 4;
    uint4 qv[8];
    #pragma unroll
    for (int i = 0; i < 8; i++) qv[i] = *(const uint4*)&qs[w][h * 72 + i * 8];
    float s[4];
    #pragma unroll
    for (int i = 0; i < 4; i++) {
        const int g = g0 * 4 + i;
        float a = 0.f;
        #pragma unroll
        for (int c = 0; c < 8; c++) {
            uint4 kv = *(const uint4*)&qs[w][(16 + g) * 72 + c * 8];
            uint qa[4] = {qv[c].x, qv[c].y, qv[c].z, qv[c].w};
            uint ka[4] = {kv.x, kv.y, kv.z, kv.w};
            #pragma unroll
            for (int u = 0; u < 4; u++) {
                a += b2f((unsigned short)qa[u]) * b2f((unsigned short)ka[u]);
                a += b2f((unsigned short)(qa[u] >> 16)) * b2f((unsigned short)(ka[u] >> 16));
            }
        }
        s[i] = a * ATT_SCALE;
    }
    float mx = fmaxf(fmaxf(s[0], s[1]), fmaxf(s[2], s[3]));
    mx = fmaxf(mx, __shfl_xor(mx, 16, 64));
    mx = fmaxf(mx, __shfl_xor(mx, 32, 64));
    float p[4], smv = 0.f;
    #pragma unroll
    for (int i = 0; i < 4; i++) { p[i] = __expf(s[i] - mx); smv += p[i]; }
    smv += __shfl_xor(smv, 16, 64);
    smv += __shfl_xor(smv, 32, 64);
    const float inv = 1.f / smv;
    #pragma unroll
    for (int i = 0; i < 4; i++) ps[w][h * 17 + g0 * 4 + i] = p[i] * inv;
    __syncthreads();

    const int h2 = lane >> 2, db = (lane & 3) * 16;
    float pr[16];
    #pragma unroll
    for (int g = 0; g < 16; g++) pr[g] = ps[w][h2 * 17 + g];
    float acc[16];
    #pragma unroll
    for (int j = 0; j < 16; j++) acc[j] = 0.f;
    #pragma unroll
    for (int g = 0; g < 16; g++) {
        const unsigned short* vp = &qs[w][(32 + g) * 72 + db];
        uint4 v0 = *(const uint4*)vp;
        uint4 v1 = *(const uint4*)(vp + 8);
        const float pg = pr[g];
        uint va[8] = {v0.x, v0.y, v0.z, v0.w, v1.x, v1.y, v1.z, v1.w};
        #pragma unroll
        for (int u = 0; u < 8; u++) {
            acc[2*u]   += pg * b2f((unsigned short)va[u]);
            acc[2*u+1] += pg * b2f((unsigned short)(va[u] >> 16));
        }
    }
    const int b = t >> 12, n = t & 4095;
    const int n1 = h2 * 256 + (n >> 4);
    const int c0 = (n & 15) * 64 + db;
    union { unsigned short u[16]; uint4 v[2]; } st;
    #pragma unroll
    for (int j = 0; j < 16; j++) st.u[j] = f2b(acc[j]);
    unsigned short* dst = outp + ((size_t)(b * SEQL + n1)) * 1024 + c0;
    *(uint4*)dst       = st.v[0];
    *(uint4*)(dst + 8) = st.v[1];
}

extern "C" void kernel_launch(void* const* d_in, const int* in_sizes, int n_in,
                              void* d_out, int out_size, void* d_ws, size_t ws_size,
                              hipStream_t stream)
{
    const float* x      = (const float*)d_in[0];
    const float* qkv_w  = (const float*)d_in[1];
    const float* qkv_b  = (const float*)d_in[2];
    const float* proj_w = (const float*)d_in[3];
    const float* proj_b = (const float*)d_in[4];

    unsigned short* xb  = (unsigned short*)d_ws;            // 33.5 MB
    unsigned short* qkv = xb + (size_t)TOK * KD;            // 100.7 MB
    unsigned short* qwb = qkv + (size_t)TOK * NQKV;         // 6.3 MB
    unsigned short* pwb = qwb + (size_t)NQKV * KD;          // 2.1 MB
    unsigned short* att = xb;                               // alias (after QKV GEMM)

    hipFuncSetAttribute(reinterpret_cast<const void*>(&gemm256<true>),
                        hipFuncAttributeMaxDynamicSharedMemorySize, 131072);
    hipFuncSetAttribute(reinterpret_cast<const void*>(&gemm256<false>),
                        hipFuncAttributeMaxDynamicSharedMemorySize, 131072);

    cvt_kernel<<<dim3(TOK * KD / 2048), dim3(256), 0, stream>>>(x, xb, TOK * KD);
    cvt_kernel<<<dim3(NQKV * KD / 2048), dim3(256), 0, stream>>>(qkv_w, qwb, NQKV * KD);
    cvt_kernel<<<dim3(KD * KD / 2048), dim3(256), 0, stream>>>(proj_w, pwb, KD * KD);

    gemm256<true><<<dim3(NQKV / 256, TOK / 256), dim3(512), 131072, stream>>>(
        xb, qwb, qkv_b, qkv, NQKV);
    attn_kernel<<<dim3(TOK / 4), dim3(256), 0, stream>>>(qkv, att);
    gemm256<false><<<dim3(KD / 256, TOK / 256), dim3(512), 131072, stream>>>(
        att, pwb, proj_b, (float*)d_out, KD);
}